// Round 1
// baseline (1284.181 us; speedup 1.0000x reference)
//
#include <hip/hip_runtime.h>
#include <hip/hip_bf16.h>

#define T_TOK 4096
#define DDIM  1024
#define FDIM  4096
#define NEXP  8

typedef __attribute__((ext_vector_type(8))) short bf16x8;
typedef __attribute__((ext_vector_type(4))) float f32x4;

__device__ __forceinline__ void gl2lds16(const void* g, void* l) {
  __builtin_amdgcn_global_load_lds((const __attribute__((address_space(1))) void*)g,
                                   (__attribute__((address_space(3))) void*)l,
                                   16, 0, 0);
}

// f32 -> bf16 round-to-nearest-even (inputs finite)
__device__ __forceinline__ unsigned short f2bf(float f) {
  unsigned u = __float_as_uint(f);
  unsigned r = (u + 0x7fffu + ((u >> 16) & 1u)) >> 16;
  return (unsigned short)r;
}

// ---------------- router: logits (f32 exact), top-2, counts, x->bf16 ----------------
__global__ __launch_bounds__(256) void moe_router(
    const float* __restrict__ x, const float* __restrict__ Wr,
    unsigned short* __restrict__ xb, int* __restrict__ te,
    float* __restrict__ tw, int* __restrict__ counts) {
  __shared__ float wr[NEXP * DDIM];  // 32 KB
  const int tid = threadIdx.x;
#pragma unroll
  for (int i = 0; i < NEXP * DDIM / 256; ++i) wr[i * 256 + tid] = Wr[i * 256 + tid];
  __syncthreads();

  const int wave = tid >> 6, lane = tid & 63;
  const int t = blockIdx.x * 4 + wave;  // 1024 blocks * 4 waves = 4096 tokens
  const float* xr = x + (size_t)t * DDIM;
  const int d0 = lane * 16;

  float4 xv[4];
#pragma unroll
  for (int j = 0; j < 4; ++j) xv[j] = *(const float4*)(xr + d0 + j * 4);

  float lg[NEXP];
#pragma unroll
  for (int e = 0; e < NEXP; ++e) {
    float s = 0.f;
#pragma unroll
    for (int j = 0; j < 4; ++j) {
      float4 wv = *(const float4*)(&wr[e * DDIM + d0 + j * 4]);
      s += xv[j].x * wv.x + xv[j].y * wv.y + xv[j].z * wv.z + xv[j].w * wv.w;
    }
    lg[e] = s;
  }
#pragma unroll
  for (int e = 0; e < NEXP; ++e) {
#pragma unroll
    for (int off = 32; off > 0; off >>= 1) lg[e] += __shfl_xor(lg[e], off);
  }

  // fused x -> bf16
#pragma unroll
  for (int j = 0; j < 4; ++j) {
    ushort4 o;
    o.x = f2bf(xv[j].x); o.y = f2bf(xv[j].y); o.z = f2bf(xv[j].z); o.w = f2bf(xv[j].w);
    *(ushort4*)(xb + (size_t)t * DDIM + d0 + j * 4) = o;
  }

  if (lane == 0) {
    int i0 = 0;
#pragma unroll
    for (int e = 1; e < NEXP; ++e) if (lg[e] > lg[i0]) i0 = e;
    int i1 = (i0 == 0) ? 1 : 0;
#pragma unroll
    for (int e = 0; e < NEXP; ++e) if (e != i0 && lg[e] > lg[i1]) i1 = e;
    // softmax over all 8 then renorm top-2 == softmax over top-2 logits
    float w0 = 1.f / (1.f + __expf(lg[i1] - lg[i0]));
    te[t * 2 + 0] = i0; te[t * 2 + 1] = i1;
    tw[t * 2 + 0] = w0; tw[t * 2 + 1] = 1.f - w0;
    atomicAdd(&counts[i0], 1);
    atomicAdd(&counts[i1], 1);
  }
}

// ---------------- tiny prefix sum over 8 experts ----------------
__global__ void moe_prefix(const int* __restrict__ counts, int* __restrict__ offs,
                           int* __restrict__ fill) {
  if (threadIdx.x == 0) {
    int s = 0;
    for (int e = 0; e < NEXP; ++e) { offs[e] = s; s += counts[e]; fill[e] = 0; }
    offs[NEXP] = s;
  }
}

// ---------------- scatter tokens into compact per-expert lists ----------------
__global__ __launch_bounds__(256) void moe_scatter(
    const int* __restrict__ te, const float* __restrict__ tw,
    const int* __restrict__ offs, int* __restrict__ fill,
    int* __restrict__ rows, float* __restrict__ wts) {
  const int t = blockIdx.x * 256 + threadIdx.x;
#pragma unroll
  for (int k = 0; k < 2; ++k) {
    int e = te[t * 2 + k];
    int pos = offs[e] + atomicAdd(&fill[e], 1);
    rows[pos] = t;
    wts[pos] = tw[t * 2 + k];
  }
}

// ---------------- grouped GEMM: 128x128 tile, BK=64, 4 waves, 16x16x32 bf16 MFMA ----
// DOSILU: out = silu(A@W) -> bf16 Hout ; else: atomicAdd(Out[token], w * (A@W))
template <int KD, int ND, bool GATHER, bool DOSILU>
__global__ __launch_bounds__(256) void moe_gemm(
    const unsigned short* __restrict__ Asrc, const float* __restrict__ Wsrc,
    const int* __restrict__ rows, const float* __restrict__ wts,
    const int* __restrict__ offs,
    unsigned short* __restrict__ Hout, float* __restrict__ Out) {
  __shared__ alignas(16) unsigned short Alds[128 * 64];  // [row][k] chunk-swizzled, 16 KB
  __shared__ alignas(16) unsigned short Blds[128 * 64];  // [col][k] chunk-swizzled, 16 KB
  __shared__ int ridlds[128];
  __shared__ int toklds[128];
  __shared__ float wlds[128];

  const int e = blockIdx.x >> 5;
  const int mt = blockIdx.x & 31;
  const int base = offs[e];
  const int cnt = offs[e + 1] - base;
  const int m0 = mt * 128;
  if (m0 >= cnt) return;
  const int valid = min(128, cnt - m0);

  const int tid = threadIdx.x;
  if (tid < 128) {
    int slot = base + m0 + min(tid, valid - 1);
    ridlds[tid] = GATHER ? rows[slot] : slot;
    if (!DOSILU) { toklds[tid] = rows[slot]; wlds[tid] = wts[slot]; }
  }
  __syncthreads();

  const float* W = Wsrc + (size_t)e * KD * ND;
  const int n0 = blockIdx.y * 128;
  const int wave = tid >> 6, lane = tid & 63;
  const int wm = wave >> 1, wn = wave & 1;

  f32x4 acc[4][4] = {};

  for (int k0 = 0; k0 < KD; k0 += 64) {
    // --- A tile: global_load_lds, LDS linear dest + inverse-swizzled per-lane source
#pragma unroll
    for (int s = 0; s < 4; ++s) {
      int c = (s * 4 + wave) * 64 + lane;  // chunk 0..1023 (16B chunks)
      int row = c >> 3, sc = c & 7;
      int cc = sc ^ (row & 7);
      const unsigned short* gp = Asrc + (size_t)ridlds[row] * KD + k0 + cc * 8;
      gl2lds16(gp, Alds + (size_t)(s * 4 + wave) * 512);
    }
    // --- B tile: f32 strided loads (wave-coalesced along n), convert, transpose to [col][k]
#pragma unroll
    for (int s = 0; s < 4; ++s) {
      int task = s * 256 + tid;           // 1024 tasks = 128 cols * 8 kgroups
      int col = task & 127, kg = task >> 7;
      const float* wp = W + (size_t)(k0 + kg * 8) * ND + n0 + col;
      unsigned short h[8];
#pragma unroll
      for (int i = 0; i < 8; ++i) h[i] = f2bf(wp[(size_t)i * ND]);
      int sc = kg ^ (col & 7);
      uint4 pk;
      pk.x = (unsigned)h[0] | ((unsigned)h[1] << 16);
      pk.y = (unsigned)h[2] | ((unsigned)h[3] << 16);
      pk.z = (unsigned)h[4] | ((unsigned)h[5] << 16);
      pk.w = (unsigned)h[6] | ((unsigned)h[7] << 16);
      *(uint4*)((char*)Blds + col * 128 + sc * 16) = pk;
    }
    __syncthreads();  // drains vmcnt (global_load_lds) + lgkm

    // --- compute: 2 k-substeps of 32, 4x4 fragments per wave
#pragma unroll
    for (int ks = 0; ks < 2; ++ks) {
      bf16x8 af[4], bfr[4];
#pragma unroll
      for (int mf = 0; mf < 4; ++mf) {
        int row = wm * 64 + mf * 16 + (lane & 15);
        int cc = ks * 4 + (lane >> 4);
        af[mf] = *(const bf16x8*)((const char*)Alds + row * 128 + ((cc ^ (row & 7)) * 16));
      }
#pragma unroll
      for (int nf = 0; nf < 4; ++nf) {
        int col = wn * 64 + nf * 16 + (lane & 15);
        int cc = ks * 4 + (lane >> 4);
        bfr[nf] = *(const bf16x8*)((const char*)Blds + col * 128 + ((cc ^ (col & 7)) * 16));
      }
#pragma unroll
      for (int mf = 0; mf < 4; ++mf)
#pragma unroll
        for (int nf = 0; nf < 4; ++nf)
          acc[mf][nf] = __builtin_amdgcn_mfma_f32_16x16x32_bf16(af[mf], bfr[nf], acc[mf][nf], 0, 0, 0);
    }
    __syncthreads();
  }

  // --- epilogue: C/D layout col=lane&15, row=(lane>>4)*4+reg
  const int q = lane >> 4, c16 = lane & 15;
#pragma unroll
  for (int mf = 0; mf < 4; ++mf) {
#pragma unroll
    for (int r = 0; r < 4; ++r) {
      int lrow = wm * 64 + mf * 16 + q * 4 + r;
      if (lrow < valid) {
#pragma unroll
        for (int nf = 0; nf < 4; ++nf) {
          int gcol = n0 + wn * 64 + nf * 16 + c16;
          float v = acc[mf][nf][r];
          if (DOSILU) {
            v = v / (1.f + __expf(-v));
            Hout[(size_t)(base + m0 + lrow) * ND + gcol] = f2bf(v);
          } else {
            atomicAdd(&Out[(size_t)toklds[lrow] * ND + gcol], v * wlds[lrow]);
          }
        }
      }
    }
  }
}

extern "C" void kernel_launch(void* const* d_in, const int* in_sizes, int n_in,
                              void* d_out, int out_size, void* d_ws, size_t ws_size,
                              hipStream_t stream) {
  const float* x  = (const float*)d_in[0];   // [2,2048,1024]
  const float* Wr = (const float*)d_in[1];   // [8,1024]
  const float* W1 = (const float*)d_in[2];   // [8,1024,4096]
  const float* W2 = (const float*)d_in[3];   // [8,4096,1024]
  float* out = (float*)d_out;                // [2,2048,1024] f32

  char* ws = (char*)d_ws;
  unsigned short* xb = (unsigned short*)ws;                       // 8 MB bf16 tokens
  unsigned short* H  = (unsigned short*)(ws + (size_t)(8 << 20)); // 64 MB bf16 hidden
  char* meta = ws + (size_t)(72 << 20);
  int*   rows   = (int*)meta;                  // 32 KB
  float* wts    = (float*)(meta + (32 << 10)); // 32 KB
  int*   te     = (int*)(meta + (64 << 10));   // 32 KB
  float* tw     = (float*)(meta + (96 << 10)); // 32 KB
  int*   counts = (int*)(meta + (128 << 10));  // 8
  int*   offs   = counts + 16;                 // 9
  int*   fill   = counts + 32;                 // 8

  hipMemsetAsync(counts, 0, 256, stream);
  hipMemsetAsync(out, 0, (size_t)out_size * sizeof(float), stream);

  moe_router<<<T_TOK / 4, 256, 0, stream>>>(x, Wr, xb, te, tw, counts);
  moe_prefix<<<1, 64, 0, stream>>>(counts, offs, fill);
  moe_scatter<<<T_TOK / 256, 256, 0, stream>>>(te, tw, offs, fill, rows, wts);

  // GEMM1: H = silu(x_gathered @ W1[e]);  grid: (8 experts * 32 m-tiles, F/128)
  moe_gemm<DDIM, FDIM, true, true><<<dim3(NEXP * 32, FDIM / 128), 256, 0, stream>>>(
      xb, W1, rows, wts, offs, H, nullptr);
  // GEMM2: out[token] += w * (H @ W2[e]); grid: (8 experts * 32 m-tiles, D/128)
  moe_gemm<FDIM, DDIM, false, false><<<dim3(NEXP * 32, DDIM / 128), 256, 0, stream>>>(
      H, W2, rows, wts, offs, nullptr, out);
}

// Round 2
// 849.556 us; speedup vs baseline: 1.5116x; 1.5116x over previous
//
#include <hip/hip_runtime.h>
#include <hip/hip_bf16.h>

#define T_TOK 4096
#define DDIM  1024
#define FDIM  4096
#define NEXP  8

typedef __attribute__((ext_vector_type(8))) short bf16x8;
typedef __attribute__((ext_vector_type(4))) float f32x4;

__device__ __forceinline__ void gl2lds16(const void* g, void* l) {
  __builtin_amdgcn_global_load_lds((const __attribute__((address_space(1))) void*)g,
                                   (__attribute__((address_space(3))) void*)l,
                                   16, 0, 0);
}

// f32 -> bf16 round-to-nearest-even (inputs finite)
__device__ __forceinline__ unsigned short f2bf(float f) {
  unsigned u = __float_as_uint(f);
  unsigned r = (u + 0x7fffu + ((u >> 16) & 1u)) >> 16;
  return (unsigned short)r;
}

// ---------------- router: logits (f32 exact), top-2, counts, x->bf16 ----------------
__global__ __launch_bounds__(256) void moe_router(
    const float* __restrict__ x, const float* __restrict__ Wr,
    unsigned short* __restrict__ xb, int* __restrict__ te,
    float* __restrict__ tw, int* __restrict__ counts) {
  __shared__ float wr[NEXP * DDIM];  // 32 KB
  const int tid = threadIdx.x;
#pragma unroll
  for (int i = 0; i < NEXP * DDIM / 256; ++i) wr[i * 256 + tid] = Wr[i * 256 + tid];
  __syncthreads();

  const int wave = tid >> 6, lane = tid & 63;
  const int t = blockIdx.x * 4 + wave;
  const float* xr = x + (size_t)t * DDIM;
  const int d0 = lane * 16;

  float4 xv[4];
#pragma unroll
  for (int j = 0; j < 4; ++j) xv[j] = *(const float4*)(xr + d0 + j * 4);

  float lg[NEXP];
#pragma unroll
  for (int e = 0; e < NEXP; ++e) {
    float s = 0.f;
#pragma unroll
    for (int j = 0; j < 4; ++j) {
      float4 wv = *(const float4*)(&wr[e * DDIM + d0 + j * 4]);
      s += xv[j].x * wv.x + xv[j].y * wv.y + xv[j].z * wv.z + xv[j].w * wv.w;
    }
    lg[e] = s;
  }
#pragma unroll
  for (int e = 0; e < NEXP; ++e) {
#pragma unroll
    for (int off = 32; off > 0; off >>= 1) lg[e] += __shfl_xor(lg[e], off);
  }

#pragma unroll
  for (int j = 0; j < 4; ++j) {
    ushort4 o;
    o.x = f2bf(xv[j].x); o.y = f2bf(xv[j].y); o.z = f2bf(xv[j].z); o.w = f2bf(xv[j].w);
    *(ushort4*)(xb + (size_t)t * DDIM + d0 + j * 4) = o;
  }

  if (lane == 0) {
    int i0 = 0;
#pragma unroll
    for (int e = 1; e < NEXP; ++e) if (lg[e] > lg[i0]) i0 = e;
    int i1 = (i0 == 0) ? 1 : 0;
#pragma unroll
    for (int e = 0; e < NEXP; ++e) if (e != i0 && lg[e] > lg[i1]) i1 = e;
    float w0 = 1.f / (1.f + __expf(lg[i1] - lg[i0]));
    te[t * 2 + 0] = i0; te[t * 2 + 1] = i1;
    tw[t * 2 + 0] = w0; tw[t * 2 + 1] = 1.f - w0;
    atomicAdd(&counts[i0], 1);
    atomicAdd(&counts[i1], 1);
  }
}

// ---------------- tiny prefix sum over 8 experts ----------------
__global__ void moe_prefix(const int* __restrict__ counts, int* __restrict__ offs,
                           int* __restrict__ fill) {
  if (threadIdx.x == 0) {
    int s = 0;
    for (int e = 0; e < NEXP; ++e) { offs[e] = s; s += counts[e]; fill[e] = 0; }
    offs[NEXP] = s;
  }
}

// ---------------- scatter tokens into compact per-expert lists ----------------
__global__ __launch_bounds__(256) void moe_scatter(
    const int* __restrict__ te, const int* __restrict__ offs, int* __restrict__ fill,
    int* __restrict__ rows, int* __restrict__ slot) {
  const int t = blockIdx.x * 256 + threadIdx.x;
#pragma unroll
  for (int k = 0; k < 2; ++k) {
    int e = te[t * 2 + k];
    int pos = offs[e] + atomicAdd(&fill[e], 1);
    rows[pos] = t;
    slot[t * 2 + k] = pos;
  }
}

// ---------------- weight convert+transpose: f32 [E][K][N] -> bf16 [E][N][K] ----------
__global__ __launch_bounds__(256) void wconv_t(const float* __restrict__ W,
                                               unsigned short* __restrict__ Wt,
                                               int K, int N) {
  __shared__ unsigned short t[64][65];
  const int e = blockIdx.z;
  const float* src = W + (size_t)e * K * N + (size_t)(blockIdx.y * 64) * N + blockIdx.x * 64;
  unsigned short* dst = Wt + (size_t)e * N * K + (size_t)(blockIdx.x * 64) * K + blockIdx.y * 64;
  const int tid = threadIdx.x;
  const int rr = tid >> 4;          // 0..15
  const int cc4 = (tid & 15) * 4;   // 0..60
#pragma unroll
  for (int i = 0; i < 4; ++i) {
    int r = i * 16 + rr;
    float4 v = *(const float4*)(src + (size_t)r * N + cc4);
    t[cc4 + 0][r] = f2bf(v.x);
    t[cc4 + 1][r] = f2bf(v.y);
    t[cc4 + 2][r] = f2bf(v.z);
    t[cc4 + 3][r] = f2bf(v.w);
  }
  __syncthreads();
#pragma unroll
  for (int i = 0; i < 4; ++i) {
    int c = i * 16 + rr;  // output row (n)
    ushort4 o;
    o.x = t[c][cc4 + 0]; o.y = t[c][cc4 + 1]; o.z = t[c][cc4 + 2]; o.w = t[c][cc4 + 3];
    *(ushort4*)(dst + (size_t)c * K + cc4) = o;
  }
}

// ---------------- grouped GEMM: 128x128 tile, BK=64, 4 waves, 16x16x32 bf16 MFMA ----
// Both A and B (pre-transposed bf16 [N][K]) staged via global_load_lds.
// DOSILU: Hout[slot][ND] = bf16(silu(A@W)) ; else: Yout[slot][ND] = f32(A@W)
template <int KD, int ND, bool GATHER, bool DOSILU>
__global__ __launch_bounds__(256) void moe_gemm(
    const unsigned short* __restrict__ Asrc, const unsigned short* __restrict__ Wt,
    const int* __restrict__ rows, const int* __restrict__ offs,
    unsigned short* __restrict__ Hout, float* __restrict__ Yout) {
  __shared__ alignas(16) unsigned short Alds[128 * 64];  // [row][k] chunk-swizzled
  __shared__ alignas(16) unsigned short Blds[128 * 64];  // [col][k] chunk-swizzled
  __shared__ int ridlds[128];

  const int e = blockIdx.x >> 5;
  const int mt = blockIdx.x & 31;
  const int base = offs[e];
  const int cnt = offs[e + 1] - base;
  const int m0 = mt * 128;
  if (m0 >= cnt) return;
  const int valid = min(128, cnt - m0);

  const int tid = threadIdx.x;
  if (tid < 128) {
    int slot = base + m0 + min(tid, valid - 1);
    ridlds[tid] = GATHER ? rows[slot] : slot;
  }
  __syncthreads();

  const int n0 = blockIdx.y * 128;
  const unsigned short* Wb = Wt + (size_t)e * ND * KD + (size_t)n0 * KD;
  const int wave = tid >> 6, lane = tid & 63;
  const int wm = wave >> 1, wn = wave & 1;

  f32x4 acc[4][4] = {};

  for (int k0 = 0; k0 < KD; k0 += 64) {
#pragma unroll
    for (int s = 0; s < 4; ++s) {
      int c = (s * 4 + wave) * 64 + lane;  // 16B chunk id 0..1023
      int row = c >> 3, sc = c & 7;
      int cc = sc ^ (row & 7);
      gl2lds16(Asrc + (size_t)ridlds[row] * KD + k0 + cc * 8,
               Alds + (size_t)(s * 4 + wave) * 512);
    }
#pragma unroll
    for (int s = 0; s < 4; ++s) {
      int c = (s * 4 + wave) * 64 + lane;
      int row = c >> 3, sc = c & 7;
      int cc = sc ^ (row & 7);
      gl2lds16(Wb + (size_t)row * KD + k0 + cc * 8,
               Blds + (size_t)(s * 4 + wave) * 512);
    }
    __syncthreads();  // drains vmcnt + lgkm

#pragma unroll
    for (int ks = 0; ks < 2; ++ks) {
      bf16x8 af[4], bfr[4];
#pragma unroll
      for (int mf = 0; mf < 4; ++mf) {
        int row = wm * 64 + mf * 16 + (lane & 15);
        int cc = ks * 4 + (lane >> 4);
        af[mf] = *(const bf16x8*)((const char*)Alds + row * 128 + ((cc ^ (row & 7)) * 16));
      }
#pragma unroll
      for (int nf = 0; nf < 4; ++nf) {
        int col = wn * 64 + nf * 16 + (lane & 15);
        int cc = ks * 4 + (lane >> 4);
        bfr[nf] = *(const bf16x8*)((const char*)Blds + col * 128 + ((cc ^ (col & 7)) * 16));
      }
#pragma unroll
      for (int mf = 0; mf < 4; ++mf)
#pragma unroll
        for (int nf = 0; nf < 4; ++nf)
          acc[mf][nf] = __builtin_amdgcn_mfma_f32_16x16x32_bf16(af[mf], bfr[nf], acc[mf][nf], 0, 0, 0);
    }
    __syncthreads();
  }

  // epilogue: C/D layout col=lane&15, row=(lane>>4)*4+reg
  const int q = lane >> 4, c16 = lane & 15;
#pragma unroll
  for (int mf = 0; mf < 4; ++mf) {
#pragma unroll
    for (int r = 0; r < 4; ++r) {
      int lrow = wm * 64 + mf * 16 + q * 4 + r;
      if (lrow < valid) {
#pragma unroll
        for (int nf = 0; nf < 4; ++nf) {
          int gcol = n0 + wn * 64 + nf * 16 + c16;
          float v = acc[mf][nf][r];
          if (DOSILU) {
            v = v / (1.f + __expf(-v));
            Hout[(size_t)(base + m0 + lrow) * ND + gcol] = f2bf(v);
          } else {
            Yout[(size_t)(base + m0 + lrow) * ND + gcol] = v;
          }
        }
      }
    }
  }
}

// ---------------- final combine: out[t] = w0*y[slot0] + w1*y[slot1] ----------------
__global__ __launch_bounds__(256) void moe_combine(
    const float* __restrict__ y, const int* __restrict__ slot,
    const float* __restrict__ tw, float* __restrict__ out) {
  const int t = blockIdx.x;
  const int s0 = slot[t * 2], s1 = slot[t * 2 + 1];
  const float w0 = tw[t * 2], w1 = tw[t * 2 + 1];
  const float4* y0 = (const float4*)(y + (size_t)s0 * DDIM);
  const float4* y1 = (const float4*)(y + (size_t)s1 * DDIM);
  float4* o = (float4*)(out + (size_t)t * DDIM);
  const int i = threadIdx.x;  // 256 threads x float4 = 1024 floats
  float4 a = y0[i], b = y1[i];
  float4 r;
  r.x = w0 * a.x + w1 * b.x;
  r.y = w0 * a.y + w1 * b.y;
  r.z = w0 * a.z + w1 * b.z;
  r.w = w0 * a.w + w1 * b.w;
  o[i] = r;
}

extern "C" void kernel_launch(void* const* d_in, const int* in_sizes, int n_in,
                              void* d_out, int out_size, void* d_ws, size_t ws_size,
                              hipStream_t stream) {
  const float* x  = (const float*)d_in[0];   // [2,2048,1024]
  const float* Wr = (const float*)d_in[1];   // [8,1024]
  const float* W1 = (const float*)d_in[2];   // [8,1024,4096]
  const float* W2 = (const float*)d_in[3];   // [8,4096,1024]
  float* out = (float*)d_out;                // [2,2048,1024] f32

  char* ws = (char*)d_ws;
  unsigned short* xb = (unsigned short*)ws;                          // 8 MB bf16 tokens
  unsigned short* H  = (unsigned short*)(ws + (size_t)(8 << 20));    // 64 MB bf16 hidden
  unsigned short* WT = (unsigned short*)(ws + (size_t)(72 << 20));   // 64 MB bf16 Wt (shared W1t/W2t)
  float*          y  = (float*)(ws + (size_t)(136 << 20));           // 32 MB f32 per-slot out
  char* meta = ws + (size_t)(168 << 20);
  int* rows   = (int*)meta;                   // 32 KB
  int* te     = (int*)(meta + (32 << 10));    // 32 KB
  float* tw   = (float*)(meta + (64 << 10));  // 32 KB
  int* slot   = (int*)(meta + (96 << 10));    // 32 KB
  int* counts = (int*)(meta + (128 << 10));
  int* offs   = counts + 16;
  int* fill   = counts + 32;

  hipMemsetAsync(counts, 0, 256, stream);

  moe_router<<<T_TOK / 4, 256, 0, stream>>>(x, Wr, xb, te, tw, counts);
  moe_prefix<<<1, 64, 0, stream>>>(counts, offs, fill);
  moe_scatter<<<T_TOK / 256, 256, 0, stream>>>(te, offs, fill, rows, slot);

  // W1 [E][D=1024][F=4096] -> WT [E][F][D]
  wconv_t<<<dim3(FDIM / 64, DDIM / 64, NEXP), 256, 0, stream>>>(W1, WT, DDIM, FDIM);
  // GEMM1: H[slot] = silu(x[rows[slot]] @ W1[e])
  moe_gemm<DDIM, FDIM, true, true><<<dim3(NEXP * 32, FDIM / 128), 256, 0, stream>>>(
      xb, WT, rows, offs, H, nullptr);

  // W2 [E][F=4096][D=1024] -> WT [E][D][F]
  wconv_t<<<dim3(DDIM / 64, FDIM / 64, NEXP), 256, 0, stream>>>(W2, WT, FDIM, DDIM);
  // GEMM2: y[slot] = H[slot] @ W2[e]
  moe_gemm<FDIM, DDIM, false, false><<<dim3(NEXP * 32, DDIM / 128), 256, 0, stream>>>(
      H, WT, nullptr, offs, nullptr, y);

  moe_combine<<<T_TOK, 256, 0, stream>>>(y, slot, tw, out);
}

// Round 3
// 478.663 us; speedup vs baseline: 2.6829x; 1.7749x over previous
//
#include <hip/hip_runtime.h>
#include <hip/hip_bf16.h>

#define T_TOK 4096
#define DDIM  1024
#define FDIM  4096
#define NEXP  8

typedef __attribute__((ext_vector_type(8))) short bf16x8;
typedef __attribute__((ext_vector_type(4))) float f32x4;

__device__ __forceinline__ void gl2lds16(const void* g, void* l) {
  __builtin_amdgcn_global_load_lds((const __attribute__((address_space(1))) void*)g,
                                   (__attribute__((address_space(3))) void*)l,
                                   16, 0, 0);
}

// f32 -> bf16 round-to-nearest-even (inputs finite)
__device__ __forceinline__ unsigned short f2bf(float f) {
  unsigned u = __float_as_uint(f);
  unsigned r = (u + 0x7fffu + ((u >> 16) & 1u)) >> 16;
  return (unsigned short)r;
}

// ---------------- router: logits (f32 exact), top-2, counts, x->bf16 ----------------
__global__ __launch_bounds__(256) void moe_router(
    const float* __restrict__ x, const float* __restrict__ Wr,
    unsigned short* __restrict__ xb, int* __restrict__ te,
    float* __restrict__ tw, int* __restrict__ counts) {
  __shared__ float wr[NEXP * DDIM];  // 32 KB
  const int tid = threadIdx.x;
#pragma unroll
  for (int i = 0; i < NEXP * DDIM / 256; ++i) wr[i * 256 + tid] = Wr[i * 256 + tid];
  __syncthreads();

  const int wave = tid >> 6, lane = tid & 63;
  const int t = blockIdx.x * 4 + wave;
  const float* xr = x + (size_t)t * DDIM;
  const int d0 = lane * 16;

  float4 xv[4];
#pragma unroll
  for (int j = 0; j < 4; ++j) xv[j] = *(const float4*)(xr + d0 + j * 4);

  float lg[NEXP];
#pragma unroll
  for (int e = 0; e < NEXP; ++e) {
    float s = 0.f;
#pragma unroll
    for (int j = 0; j < 4; ++j) {
      float4 wv = *(const float4*)(&wr[e * DDIM + d0 + j * 4]);
      s += xv[j].x * wv.x + xv[j].y * wv.y + xv[j].z * wv.z + xv[j].w * wv.w;
    }
    lg[e] = s;
  }
#pragma unroll
  for (int e = 0; e < NEXP; ++e) {
#pragma unroll
    for (int off = 32; off > 0; off >>= 1) lg[e] += __shfl_xor(lg[e], off);
  }

#pragma unroll
  for (int j = 0; j < 4; ++j) {
    ushort4 o;
    o.x = f2bf(xv[j].x); o.y = f2bf(xv[j].y); o.z = f2bf(xv[j].z); o.w = f2bf(xv[j].w);
    *(ushort4*)(xb + (size_t)t * DDIM + d0 + j * 4) = o;
  }

  if (lane == 0) {
    int i0 = 0;
#pragma unroll
    for (int e = 1; e < NEXP; ++e) if (lg[e] > lg[i0]) i0 = e;
    int i1 = (i0 == 0) ? 1 : 0;
#pragma unroll
    for (int e = 0; e < NEXP; ++e) if (e != i0 && lg[e] > lg[i1]) i1 = e;
    float w0 = 1.f / (1.f + __expf(lg[i1] - lg[i0]));
    te[t * 2 + 0] = i0; te[t * 2 + 1] = i1;
    tw[t * 2 + 0] = w0; tw[t * 2 + 1] = 1.f - w0;
    atomicAdd(&counts[i0], 1);
    atomicAdd(&counts[i1], 1);
  }
}

// ---------------- tiny prefix sum over 8 experts ----------------
__global__ void moe_prefix(const int* __restrict__ counts, int* __restrict__ offs,
                           int* __restrict__ fill) {
  if (threadIdx.x == 0) {
    int s = 0;
    for (int e = 0; e < NEXP; ++e) { offs[e] = s; s += counts[e]; fill[e] = 0; }
    offs[NEXP] = s;
  }
}

// ---------------- scatter tokens into compact per-expert lists ----------------
__global__ __launch_bounds__(256) void moe_scatter(
    const int* __restrict__ te, const int* __restrict__ offs, int* __restrict__ fill,
    int* __restrict__ rows, int* __restrict__ slot) {
  const int t = blockIdx.x * 256 + threadIdx.x;
#pragma unroll
  for (int k = 0; k < 2; ++k) {
    int e = te[t * 2 + k];
    int pos = offs[e] + atomicAdd(&fill[e], 1);
    rows[pos] = t;
    slot[t * 2 + k] = pos;
  }
}

// ---------------- weight convert+transpose: f32 [E][K][N] -> bf16 [E][N][K] ----------
__global__ __launch_bounds__(256) void wconv_t(const float* __restrict__ W,
                                               unsigned short* __restrict__ Wt,
                                               int K, int N) {
  __shared__ unsigned short t[64][65];
  const int e = blockIdx.z;
  const float* src = W + (size_t)e * K * N + (size_t)(blockIdx.y * 64) * N + blockIdx.x * 64;
  unsigned short* dst = Wt + (size_t)e * N * K + (size_t)(blockIdx.x * 64) * K + blockIdx.y * 64;
  const int tid = threadIdx.x;
  const int rr = tid >> 4;          // 0..15
  const int cc4 = (tid & 15) * 4;   // 0..60
#pragma unroll
  for (int i = 0; i < 4; ++i) {
    int r = i * 16 + rr;
    float4 v = *(const float4*)(src + (size_t)r * N + cc4);
    t[cc4 + 0][r] = f2bf(v.x);
    t[cc4 + 1][r] = f2bf(v.y);
    t[cc4 + 2][r] = f2bf(v.z);
    t[cc4 + 3][r] = f2bf(v.w);
  }
  __syncthreads();
#pragma unroll
  for (int i = 0; i < 4; ++i) {
    int c = i * 16 + rr;  // output row (n)
    ushort4 o;
    o.x = t[c][cc4 + 0]; o.y = t[c][cc4 + 1]; o.z = t[c][cc4 + 2]; o.w = t[c][cc4 + 3];
    *(ushort4*)(dst + (size_t)c * K + cc4) = o;
  }
}

// ---------------- grouped GEMM: 128x128 tile, BK=64, 2-phase dbuf, counted vmcnt ----
// A (bf16 [row][K]) and B (bf16 [N][K]) both staged via global_load_lds.
// DOSILU: Hout[slot][ND] = bf16(silu(A@W)) ; else: Yout[slot][ND] = f32(A@W)
template <int KD, int ND, bool GATHER, bool DOSILU>
__global__ __launch_bounds__(256) void moe_gemm(
    const unsigned short* __restrict__ Asrc, const unsigned short* __restrict__ Wt,
    const int* __restrict__ rows, const int* __restrict__ offs,
    unsigned short* __restrict__ Hout, float* __restrict__ Yout, int nb) {
  __shared__ alignas(16) unsigned short Alds[2][128 * 64];  // 2 x 16 KB, chunk-swizzled
  __shared__ alignas(16) unsigned short Blds[2][128 * 64];
  __shared__ int ridlds[128];

  // bijective XCD-chunked remap (nb % 8 == 0): one XCD works one n-tile group
  const int bid = blockIdx.x;
  const int orig = (bid & 7) * (nb >> 3) + (bid >> 3);
  const int nt = orig >> 8;                // orig / (NEXP*32)
  const int em = orig & 255;
  const int e = em >> 5, mt = em & 31;

  const int base = offs[e];
  const int cnt = offs[e + 1] - base;
  const int m0 = mt * 128;
  if (m0 >= cnt) return;
  const int valid = min(128, cnt - m0);

  const int tid = threadIdx.x;
  if (tid < 128) {
    int slot = base + m0 + min(tid, valid - 1);
    ridlds[tid] = GATHER ? rows[slot] : slot;
  }
  __syncthreads();

  const int n0 = nt * 128;
  const unsigned short* Wb = Wt + (size_t)e * ND * KD + (size_t)n0 * KD;
  const int wave = tid >> 6, lane = tid & 63;
  const int wm = wave >> 1, wn = wave & 1;

  // hoisted per-thread staging addresses: thread loads rows r_s = (s*4+wave)*8+(lane>>3),
  // 16B chunk (lane&7)^(row&7) of each row (row&7 == lane>>3 since base is mult of 8)
  const int cc8 = ((lane & 7) ^ (lane >> 3)) * 8;
  size_t aoff[4], boff[4];
#pragma unroll
  for (int s = 0; s < 4; ++s) {
    int r = (s * 4 + wave) * 8 + (lane >> 3);
    aoff[s] = (size_t)ridlds[r] * KD + cc8;
    boff[s] = (size_t)r * KD + cc8;
  }

  f32x4 acc[4][4] = {};

#define STAGE(b, k0)                                                        \
  {                                                                         \
    _Pragma("unroll") for (int s = 0; s < 4; ++s)                           \
        gl2lds16(Asrc + aoff[s] + (k0), &Alds[b][(s * 4 + wave) * 512]);    \
    _Pragma("unroll") for (int s = 0; s < 4; ++s)                           \
        gl2lds16(Wb + boff[s] + (k0), &Blds[b][(s * 4 + wave) * 512]);      \
  }

#define COMPUTE(b)                                                          \
  {                                                                         \
    _Pragma("unroll") for (int ks = 0; ks < 2; ++ks) {                      \
      bf16x8 af[4], bfr[4];                                                 \
      _Pragma("unroll") for (int mf = 0; mf < 4; ++mf) {                    \
        int row = wm * 64 + mf * 16 + (lane & 15);                          \
        int cc = ks * 4 + (lane >> 4);                                      \
        af[mf] = *(const bf16x8*)((const char*)&Alds[b][0] + row * 128 +    \
                                  ((cc ^ (row & 7)) * 16));                 \
      }                                                                     \
      _Pragma("unroll") for (int nf = 0; nf < 4; ++nf) {                    \
        int col = wn * 64 + nf * 16 + (lane & 15);                          \
        int cc = ks * 4 + (lane >> 4);                                      \
        bfr[nf] = *(const bf16x8*)((const char*)&Blds[b][0] + col * 128 +   \
                                   ((cc ^ (col & 7)) * 16));                \
      }                                                                     \
      _Pragma("unroll") for (int mf = 0; mf < 4; ++mf)                      \
          _Pragma("unroll") for (int nf = 0; nf < 4; ++nf)                  \
              acc[mf][nf] = __builtin_amdgcn_mfma_f32_16x16x32_bf16(        \
                  af[mf], bfr[nf], acc[mf][nf], 0, 0, 0);                   \
    }                                                                       \
  }

  constexpr int NK = KD / 64;  // 16 or 64, always even
  STAGE(0, 0);
  for (int t = 0; t < NK; t += 2) {
    // tile t in buf0; stage t+1 into buf1 (t+1 < NK always: NK even)
    STAGE(1, (t + 1) * 64);
    asm volatile("s_waitcnt vmcnt(8)" ::: "memory");  // tile t landed; t+1 in flight
    __builtin_amdgcn_s_barrier();
    COMPUTE(0);
    __builtin_amdgcn_s_barrier();  // all waves done reading buf0
    // tile t+1 in buf1; stage t+2 into buf0
    if (t + 2 < NK) {
      STAGE(0, (t + 2) * 64);
      asm volatile("s_waitcnt vmcnt(8)" ::: "memory");
    } else {
      asm volatile("s_waitcnt vmcnt(0)" ::: "memory");
    }
    __builtin_amdgcn_s_barrier();
    COMPUTE(1);
    __builtin_amdgcn_s_barrier();
  }
#undef STAGE
#undef COMPUTE

  // epilogue: C/D layout col=lane&15, row=(lane>>4)*4+reg
  const int q = lane >> 4, c16 = lane & 15;
#pragma unroll
  for (int mf = 0; mf < 4; ++mf) {
#pragma unroll
    for (int r = 0; r < 4; ++r) {
      int lrow = wm * 64 + mf * 16 + q * 4 + r;
      if (lrow < valid) {
#pragma unroll
        for (int nf = 0; nf < 4; ++nf) {
          int gcol = n0 + wn * 64 + nf * 16 + c16;
          float v = acc[mf][nf][r];
          if (DOSILU) {
            v = v / (1.f + __expf(-v));
            Hout[(size_t)(base + m0 + lrow) * ND + gcol] = f2bf(v);
          } else {
            Yout[(size_t)(base + m0 + lrow) * ND + gcol] = v;
          }
        }
      }
    }
  }
}

// ---------------- final combine: out[t] = w0*y[slot0] + w1*y[slot1] ----------------
__global__ __launch_bounds__(256) void moe_combine(
    const float* __restrict__ y, const int* __restrict__ slot,
    const float* __restrict__ tw, float* __restrict__ out) {
  const int t = blockIdx.x;
  const int s0 = slot[t * 2], s1 = slot[t * 2 + 1];
  const float w0 = tw[t * 2], w1 = tw[t * 2 + 1];
  const float4* y0 = (const float4*)(y + (size_t)s0 * DDIM);
  const float4* y1 = (const float4*)(y + (size_t)s1 * DDIM);
  float4* o = (float4*)(out + (size_t)t * DDIM);
  const int i = threadIdx.x;
  float4 a = y0[i], b = y1[i];
  float4 r;
  r.x = w0 * a.x + w1 * b.x;
  r.y = w0 * a.y + w1 * b.y;
  r.z = w0 * a.z + w1 * b.z;
  r.w = w0 * a.w + w1 * b.w;
  o[i] = r;
}

extern "C" void kernel_launch(void* const* d_in, const int* in_sizes, int n_in,
                              void* d_out, int out_size, void* d_ws, size_t ws_size,
                              hipStream_t stream) {
  const float* x  = (const float*)d_in[0];   // [2,2048,1024]
  const float* Wr = (const float*)d_in[1];   // [8,1024]
  const float* W1 = (const float*)d_in[2];   // [8,1024,4096]
  const float* W2 = (const float*)d_in[3];   // [8,4096,1024]
  float* out = (float*)d_out;                // [2,2048,1024] f32

  char* ws = (char*)d_ws;
  unsigned short* xb = (unsigned short*)ws;                          // 8 MB bf16 tokens
  unsigned short* H  = (unsigned short*)(ws + (size_t)(8 << 20));    // 64 MB bf16 hidden
  unsigned short* WT = (unsigned short*)(ws + (size_t)(72 << 20));   // 64 MB bf16 Wt (shared)
  float*          y  = (float*)(ws + (size_t)(136 << 20));           // 32 MB f32 per-slot out
  char* meta = ws + (size_t)(168 << 20);
  int* rows   = (int*)meta;                   // 32 KB
  int* te     = (int*)(meta + (32 << 10));    // 32 KB
  float* tw   = (float*)(meta + (64 << 10));  // 32 KB
  int* slot   = (int*)(meta + (96 << 10));    // 32 KB
  int* counts = (int*)(meta + (128 << 10));
  int* offs   = counts + 16;
  int* fill   = counts + 32;

  hipMemsetAsync(counts, 0, 256, stream);

  moe_router<<<T_TOK / 4, 256, 0, stream>>>(x, Wr, xb, te, tw, counts);
  moe_prefix<<<1, 64, 0, stream>>>(counts, offs, fill);
  moe_scatter<<<T_TOK / 256, 256, 0, stream>>>(te, offs, fill, rows, slot);

  // W1 [E][D=1024][F=4096] -> WT [E][F][D]
  wconv_t<<<dim3(FDIM / 64, DDIM / 64, NEXP), 256, 0, stream>>>(W1, WT, DDIM, FDIM);
  // GEMM1: H[slot] = silu(x[rows[slot]] @ W1[e]);  1-D grid, XCD-chunked
  moe_gemm<DDIM, FDIM, true, true><<<NEXP * 32 * (FDIM / 128), 256, 0, stream>>>(
      xb, WT, rows, offs, H, nullptr, NEXP * 32 * (FDIM / 128));

  // W2 [E][F=4096][D=1024] -> WT [E][D][F]
  wconv_t<<<dim3(DDIM / 64, FDIM / 64, NEXP), 256, 0, stream>>>(W2, WT, FDIM, DDIM);
  // GEMM2: y[slot] = H[slot] @ W2[e]
  moe_gemm<FDIM, DDIM, false, false><<<NEXP * 32 * (DDIM / 128), 256, 0, stream>>>(
      H, WT, nullptr, offs, nullptr, y, NEXP * 32 * (DDIM / 128));

  moe_combine<<<T_TOK, 256, 0, stream>>>(y, slot, tw, out);
}

// Round 4
// 472.062 us; speedup vs baseline: 2.7204x; 1.0140x over previous
//
#include <hip/hip_runtime.h>
#include <hip/hip_bf16.h>

#define T_TOK 4096
#define DDIM  1024
#define FDIM  4096
#define NEXP  8

typedef __attribute__((ext_vector_type(8))) short bf16x8;
typedef __attribute__((ext_vector_type(4))) float f32x4;

__device__ __forceinline__ void gl2lds16(const void* g, void* l) {
  __builtin_amdgcn_global_load_lds((const __attribute__((address_space(1))) void*)g,
                                   (__attribute__((address_space(3))) void*)l,
                                   16, 0, 0);
}

// f32 -> bf16 round-to-nearest-even (inputs finite)
__device__ __forceinline__ unsigned short f2bf(float f) {
  unsigned u = __float_as_uint(f);
  unsigned r = (u + 0x7fffu + ((u >> 16) & 1u)) >> 16;
  return (unsigned short)r;
}

// ---------------- router: logits (f32 exact), top-2, counts, x->bf16 ----------------
__global__ __launch_bounds__(256) void moe_router(
    const float* __restrict__ x, const float* __restrict__ Wr,
    unsigned short* __restrict__ xb, int* __restrict__ te,
    float* __restrict__ tw, int* __restrict__ counts) {
  __shared__ float wr[NEXP * DDIM];  // 32 KB
  const int tid = threadIdx.x;
#pragma unroll
  for (int i = 0; i < NEXP * DDIM / 256; ++i) wr[i * 256 + tid] = Wr[i * 256 + tid];
  __syncthreads();

  const int wave = tid >> 6, lane = tid & 63;
  const int t = blockIdx.x * 4 + wave;
  const float* xr = x + (size_t)t * DDIM;
  const int d0 = lane * 16;

  float4 xv[4];
#pragma unroll
  for (int j = 0; j < 4; ++j) xv[j] = *(const float4*)(xr + d0 + j * 4);

  float lg[NEXP];
#pragma unroll
  for (int e = 0; e < NEXP; ++e) {
    float s = 0.f;
#pragma unroll
    for (int j = 0; j < 4; ++j) {
      float4 wv = *(const float4*)(&wr[e * DDIM + d0 + j * 4]);
      s += xv[j].x * wv.x + xv[j].y * wv.y + xv[j].z * wv.z + xv[j].w * wv.w;
    }
    lg[e] = s;
  }
#pragma unroll
  for (int e = 0; e < NEXP; ++e) {
#pragma unroll
    for (int off = 32; off > 0; off >>= 1) lg[e] += __shfl_xor(lg[e], off);
  }

#pragma unroll
  for (int j = 0; j < 4; ++j) {
    ushort4 o;
    o.x = f2bf(xv[j].x); o.y = f2bf(xv[j].y); o.z = f2bf(xv[j].z); o.w = f2bf(xv[j].w);
    *(ushort4*)(xb + (size_t)t * DDIM + d0 + j * 4) = o;
  }

  if (lane == 0) {
    int i0 = 0;
#pragma unroll
    for (int e = 1; e < NEXP; ++e) if (lg[e] > lg[i0]) i0 = e;
    int i1 = (i0 == 0) ? 1 : 0;
#pragma unroll
    for (int e = 0; e < NEXP; ++e) if (e != i0 && lg[e] > lg[i1]) i1 = e;
    float w0 = 1.f / (1.f + __expf(lg[i1] - lg[i0]));
    te[t * 2 + 0] = i0; te[t * 2 + 1] = i1;
    tw[t * 2 + 0] = w0; tw[t * 2 + 1] = 1.f - w0;
    atomicAdd(&counts[i0], 1);
    atomicAdd(&counts[i1], 1);
  }
}

// ---------------- tiny prefix sum over 8 experts ----------------
__global__ void moe_prefix(const int* __restrict__ counts, int* __restrict__ offs,
                           int* __restrict__ fill) {
  if (threadIdx.x == 0) {
    int s = 0;
    for (int e = 0; e < NEXP; ++e) { offs[e] = s; s += counts[e]; fill[e] = 0; }
    offs[NEXP] = s;
  }
}

// ---------------- scatter tokens into compact per-expert lists ----------------
__global__ __launch_bounds__(256) void moe_scatter(
    const int* __restrict__ te, const int* __restrict__ offs, int* __restrict__ fill,
    int* __restrict__ rows, int* __restrict__ slot) {
  const int t = blockIdx.x * 256 + threadIdx.x;
#pragma unroll
  for (int k = 0; k < 2; ++k) {
    int e = te[t * 2 + k];
    int pos = offs[e] + atomicAdd(&fill[e], 1);
    rows[pos] = t;
    slot[t * 2 + k] = pos;
  }
}

// ---------------- weight convert+transpose: f32 [E][K][N] -> bf16 [E][N][K] ----------
__global__ __launch_bounds__(256) void wconv_t(const float* __restrict__ W,
                                               unsigned short* __restrict__ Wt,
                                               int K, int N) {
  __shared__ unsigned short t[64][65];
  const int e = blockIdx.z;
  const float* src = W + (size_t)e * K * N + (size_t)(blockIdx.y * 64) * N + blockIdx.x * 64;
  unsigned short* dst = Wt + (size_t)e * N * K + (size_t)(blockIdx.x * 64) * K + blockIdx.y * 64;
  const int tid = threadIdx.x;
  const int rr = tid >> 4;          // 0..15
  const int cc4 = (tid & 15) * 4;   // 0..60
#pragma unroll
  for (int i = 0; i < 4; ++i) {
    int r = i * 16 + rr;
    float4 v = *(const float4*)(src + (size_t)r * N + cc4);
    t[cc4 + 0][r] = f2bf(v.x);
    t[cc4 + 1][r] = f2bf(v.y);
    t[cc4 + 2][r] = f2bf(v.z);
    t[cc4 + 3][r] = f2bf(v.w);
  }
  __syncthreads();
  const int k8 = (tid & 7) * 8;     // 0..56
#pragma unroll
  for (int i = 0; i < 2; ++i) {
    int c = i * 32 + (tid >> 3);    // output row (n), 0..63
    uint4 pk;
    pk.x = (unsigned)t[c][k8 + 0] | ((unsigned)t[c][k8 + 1] << 16);
    pk.y = (unsigned)t[c][k8 + 2] | ((unsigned)t[c][k8 + 3] << 16);
    pk.z = (unsigned)t[c][k8 + 4] | ((unsigned)t[c][k8 + 5] << 16);
    pk.w = (unsigned)t[c][k8 + 6] | ((unsigned)t[c][k8 + 7] << 16);
    *(uint4*)(dst + (size_t)c * K + k8) = pk;
  }
}

// ------- grouped GEMM: BMxBN tile, BK=64, 512 thr / 8 waves (2Mx4N), 2-phase dbuf ----
// A (bf16 [row][K]) and B (bf16 [N][K]) staged via global_load_lds, XOR-swizzled.
// DOSILU: Hout[slot][ND] = bf16(silu(A@W)) ; else: Yout[slot][ND] = f32(A@W)
template <int BM, int BN, int KD, int ND, bool GATHER, bool DOSILU>
__global__ __launch_bounds__(512) void moe_gemm(
    const unsigned short* __restrict__ Asrc, const unsigned short* __restrict__ Wt,
    const int* __restrict__ rows, const int* __restrict__ offs,
    unsigned short* __restrict__ Hout, float* __restrict__ Yout) {
  constexpr int MT_MAX = 4096 / BM;       // worst-case m-tiles per expert
  constexpr int NTILE  = ND / BN;
  constexpr int NB     = NEXP * MT_MAX * NTILE;  // grid size (multiple of 8)
  constexpr int CA = BM / 64, CB = BN / 64;      // gl2lds per thread per tile
  constexpr int MF = BM / 32, NF = BN / 64;      // frags per wave
  constexpr int TOT = CA + CB;

  __shared__ alignas(16) unsigned short Alds[2][BM * 64];
  __shared__ alignas(16) unsigned short Blds[2][BN * 64];
  __shared__ int ridlds[BM];

  // bijective XCD-chunked remap; nt-major so one XCD shares B panels in L2
  const int bid = blockIdx.x;
  const int orig = (bid & 7) * (NB >> 3) + (bid >> 3);
  const int nt = orig / (NEXP * MT_MAX);
  const int rem = orig % (NEXP * MT_MAX);
  const int e = rem / MT_MAX, mt = rem % MT_MAX;

  const int base = offs[e];
  const int cnt = offs[e + 1] - base;
  const int m0 = mt * BM;
  if (m0 >= cnt) return;
  const int valid = min(BM, cnt - m0);

  const int tid = threadIdx.x;
  const int w = tid >> 6, lane = tid & 63;

  if (GATHER) {
    if (tid < BM) {
      int slot = base + m0 + min(tid, valid - 1);
      ridlds[tid] = rows[slot];
    }
    __syncthreads();
  }

  const int n0 = nt * BN;
  const unsigned short* Wb = Wt + (size_t)e * ND * KD + (size_t)n0 * KD;
  const int wm = w >> 2, wn = w & 3;

  // hoisted staging addresses: chunk c = s*512 + w*64 + lane; row=c>>3, swz chunk
  const int cc8 = ((lane & 7) ^ (lane >> 3)) * 8;
  size_t aoff[CA], boff[CB];
#pragma unroll
  for (int s = 0; s < CA; ++s) {
    int r = s * 64 + w * 8 + (lane >> 3);
    int rid = GATHER ? ridlds[r] : (base + m0 + min(r, valid - 1));
    aoff[s] = (size_t)rid * KD + cc8;
  }
#pragma unroll
  for (int s = 0; s < CB; ++s) {
    int r = s * 64 + w * 8 + (lane >> 3);
    boff[s] = (size_t)r * KD + cc8;
  }

  f32x4 acc[MF][NF] = {};

#define STAGE(b, k0)                                                         \
  {                                                                          \
    _Pragma("unroll") for (int s = 0; s < CA; ++s)                           \
        gl2lds16(Asrc + aoff[s] + (k0), &Alds[b][(s * 512 + w * 64) * 8]);   \
    _Pragma("unroll") for (int s = 0; s < CB; ++s)                           \
        gl2lds16(Wb + boff[s] + (k0), &Blds[b][(s * 512 + w * 64) * 8]);     \
  }

#define WAITCUR()                                                            \
  {                                                                          \
    if (TOT == 8) asm volatile("s_waitcnt vmcnt(8)" ::: "memory");           \
    else          asm volatile("s_waitcnt vmcnt(6)" ::: "memory");           \
  }

#define COMPUTE(b)                                                           \
  {                                                                          \
    _Pragma("unroll") for (int ks = 0; ks < 2; ++ks) {                       \
      bf16x8 af[MF], bfr[NF];                                                \
      _Pragma("unroll") for (int mf = 0; mf < MF; ++mf) {                    \
        int row = wm * (BM / 2) + mf * 16 + (lane & 15);                     \
        int cc = ks * 4 + (lane >> 4);                                       \
        af[mf] = *(const bf16x8*)((const char*)&Alds[b][0] + row * 128 +     \
                                  ((cc ^ (row & 7)) * 16));                  \
      }                                                                      \
      _Pragma("unroll") for (int nf = 0; nf < NF; ++nf) {                    \
        int col = wn * (BN / 4) + nf * 16 + (lane & 15);                     \
        int cc = ks * 4 + (lane >> 4);                                       \
        bfr[nf] = *(const bf16x8*)((const char*)&Blds[b][0] + col * 128 +    \
                                   ((cc ^ (col & 7)) * 16));                 \
      }                                                                      \
      _Pragma("unroll") for (int mf = 0; mf < MF; ++mf)                      \
          _Pragma("unroll") for (int nf = 0; nf < NF; ++nf)                  \
              acc[mf][nf] = __builtin_amdgcn_mfma_f32_16x16x32_bf16(         \
                  af[mf], bfr[nf], acc[mf][nf], 0, 0, 0);                    \
    }                                                                        \
  }

  constexpr int NK = KD / 64;  // 16 or 64, always even
  STAGE(0, 0);
  for (int t = 0; t < NK; t += 2) {
    STAGE(1, (t + 1) * 64);
    WAITCUR();  // tile t landed; t+1 stays in flight across barriers
    __builtin_amdgcn_s_barrier();
    COMPUTE(0);
    __builtin_amdgcn_s_barrier();
    if (t + 2 < NK) {
      STAGE(0, (t + 2) * 64);
      WAITCUR();
    } else {
      asm volatile("s_waitcnt vmcnt(0)" ::: "memory");
    }
    __builtin_amdgcn_s_barrier();
    COMPUTE(1);
    __builtin_amdgcn_s_barrier();
  }
#undef STAGE
#undef WAITCUR
#undef COMPUTE

  // epilogue: C/D layout col=lane&15, row=(lane>>4)*4+reg
  const int q = lane >> 4, c16 = lane & 15;
#pragma unroll
  for (int mf = 0; mf < MF; ++mf) {
#pragma unroll
    for (int r = 0; r < 4; ++r) {
      int lrow = wm * (BM / 2) + mf * 16 + q * 4 + r;
      if (lrow < valid) {
#pragma unroll
        for (int nf = 0; nf < NF; ++nf) {
          int gcol = n0 + wn * (BN / 4) + nf * 16 + c16;
          float v = acc[mf][nf][r];
          if (DOSILU) {
            v = v / (1.f + __expf(-v));
            Hout[(size_t)(base + m0 + lrow) * ND + gcol] = f2bf(v);
          } else {
            Yout[(size_t)(base + m0 + lrow) * ND + gcol] = v;
          }
        }
      }
    }
  }
}

// ---------------- final combine: out[t] = w0*y[slot0] + w1*y[slot1] ----------------
__global__ __launch_bounds__(256) void moe_combine(
    const float* __restrict__ y, const int* __restrict__ slot,
    const float* __restrict__ tw, float* __restrict__ out) {
  const int t = blockIdx.x;
  const int s0 = slot[t * 2], s1 = slot[t * 2 + 1];
  const float w0 = tw[t * 2], w1 = tw[t * 2 + 1];
  const float4* y0 = (const float4*)(y + (size_t)s0 * DDIM);
  const float4* y1 = (const float4*)(y + (size_t)s1 * DDIM);
  float4* o = (float4*)(out + (size_t)t * DDIM);
  const int i = threadIdx.x;
  float4 a = y0[i], b = y1[i];
  float4 r;
  r.x = w0 * a.x + w1 * b.x;
  r.y = w0 * a.y + w1 * b.y;
  r.z = w0 * a.z + w1 * b.z;
  r.w = w0 * a.w + w1 * b.w;
  o[i] = r;
}

extern "C" void kernel_launch(void* const* d_in, const int* in_sizes, int n_in,
                              void* d_out, int out_size, void* d_ws, size_t ws_size,
                              hipStream_t stream) {
  const float* x  = (const float*)d_in[0];   // [2,2048,1024]
  const float* Wr = (const float*)d_in[1];   // [8,1024]
  const float* W1 = (const float*)d_in[2];   // [8,1024,4096]
  const float* W2 = (const float*)d_in[3];   // [8,4096,1024]
  float* out = (float*)d_out;                // [2,2048,1024] f32

  char* ws = (char*)d_ws;
  unsigned short* xb = (unsigned short*)ws;                          // 8 MB bf16 tokens
  unsigned short* H  = (unsigned short*)(ws + (size_t)(8 << 20));    // 64 MB bf16 hidden
  unsigned short* WT = (unsigned short*)(ws + (size_t)(72 << 20));   // 64 MB bf16 Wt (shared)
  float*          y  = (float*)(ws + (size_t)(136 << 20));           // 32 MB f32 per-slot out
  char* meta = ws + (size_t)(168 << 20);
  int* rows   = (int*)meta;                   // 32 KB
  int* te     = (int*)(meta + (32 << 10));    // 32 KB
  float* tw   = (float*)(meta + (64 << 10));  // 32 KB
  int* slot   = (int*)(meta + (96 << 10));    // 32 KB
  int* counts = (int*)(meta + (128 << 10));
  int* offs   = counts + 16;
  int* fill   = counts + 32;

  hipMemsetAsync(counts, 0, 256, stream);

  moe_router<<<T_TOK / 4, 256, 0, stream>>>(x, Wr, xb, te, tw, counts);
  moe_prefix<<<1, 64, 0, stream>>>(counts, offs, fill);
  moe_scatter<<<T_TOK / 256, 256, 0, stream>>>(te, offs, fill, rows, slot);

  // W1 [E][D=1024][F=4096] -> WT [E][F][D]
  wconv_t<<<dim3(FDIM / 64, DDIM / 64, NEXP), 256, 0, stream>>>(W1, WT, DDIM, FDIM);
  // GEMM1: H[slot] = silu(x[rows[slot]] @ W1[e]); 256x256 tile
  moe_gemm<256, 256, DDIM, FDIM, true, true>
      <<<NEXP * (4096 / 256) * (FDIM / 256), 512, 0, stream>>>(xb, WT, rows, offs, H, nullptr);

  // W2 [E][F=4096][D=1024] -> WT [E][D][F]
  wconv_t<<<dim3(DDIM / 64, FDIM / 64, NEXP), 256, 0, stream>>>(W2, WT, FDIM, DDIM);
  // GEMM2: y[slot] = H[slot] @ W2[e]; 128x256 tile
  moe_gemm<128, 256, FDIM, DDIM, false, false>
      <<<NEXP * (4096 / 128) * (DDIM / 256), 512, 0, stream>>>(H, WT, nullptr, offs, nullptr, y);

  moe_combine<<<T_TOK, 256, 0, stream>>>(y, slot, tw, out);
}